// Round 10
// baseline (239.025 us; speedup 1.0000x reference)
//
#include <hip/hip_runtime.h>
#include <hip/hip_bf16.h>

// B=128, D=64.
//   c_vec[b,c] = mean_{h,w} x[b,c,h,w]
//   h_vec[b,w] = mean_{c,h} x[b,c,h,w]
//   w_vec[b,h] = mean_{c,w} x[b,c,h,w]
//   f*[b,i,o] = sigmoid(sum_j W*[i,o,j] * vec[b,j])
//   LR[b,c,p,q] = sum_i fc[b,i,c]*fh[b,i,p]*fw[b,i,q]
// R10: single fused kernel with HAND-ROLLED grid barriers (cooperative launch
// failed silently in R9). Co-residency by construction: 512 blocks, 2/CU
// (launch_bounds(256,2) -> VGPR<=256 -> 8 waves/CU; 48KB LDS -> 3/CU) so all
// 512 resident -> barrier safe. Device-scope fences handle cross-XCD L2.
// Barrier counters in d_ws, zeroed per call via 8-byte hipMemsetAsync.

#define NB 128

typedef __attribute__((ext_vector_type(8))) short bf16x8;
typedef __attribute__((ext_vector_type(4))) float f32x4;

__device__ __forceinline__ float bf2f(short s) {
    return __uint_as_float(((unsigned)(unsigned short)s) << 16);
}
__device__ __forceinline__ unsigned packbf2(float a, float b) {
    unsigned ua = __float_as_uint(a); ua += 0x7fffu + ((ua >> 16) & 1u);
    unsigned ub = __float_as_uint(b); ub += 0x7fffu + ((ub >> 16) & 1u);
    return (ua >> 16) | (ub & 0xffff0000u);
}
__device__ __forceinline__ unsigned short f2bf(float f) {
    unsigned u = __float_as_uint(f); u += 0x7fffu + ((u >> 16) & 1u);
    return (unsigned short)(u >> 16);
}

// Grid barrier: all `target` blocks arrive, with device-scope release/acquire
// so data written before the barrier is visible across XCDs after it.
__device__ __forceinline__ void grid_barrier(unsigned* cnt, unsigned target) {
    __syncthreads();                 // block's global writes drained (vmcnt(0))
    if (threadIdx.x == 0) {
        __threadfence();             // agent release: L2 writeback
        atomicAdd(cnt, 1u);          // device-scope (LLC) counter
        while (__hip_atomic_load(cnt, __ATOMIC_RELAXED,
                                 __HIP_MEMORY_SCOPE_AGENT) < target) {
            __builtin_amdgcn_s_sleep(2);
        }
        __threadfence();             // agent acquire: L2/L1 invalidate
    }
    __syncthreads();
}

__global__ __launch_bounds__(256, 2) void fused_kernel(
    const float* __restrict__ x,
    const float* __restrict__ Wc,
    const float* __restrict__ Wh,
    const float* __restrict__ Ww,
    float* __restrict__ cvecT,    // [64][128]
    float* __restrict__ hv_part,  // [4][64][128] per-w (ref h_vec)
    float* __restrict__ wv_part,  // [4][64][128] per-h (ref w_vec)
    unsigned short* __restrict__ fcT,  // bf16 [b][o][i]
    unsigned short* __restrict__ fhT,
    unsigned short* __restrict__ fwT,
    unsigned* __restrict__ bar,        // 2 counters, zeroed per call
    float* __restrict__ out)
{
    __shared__ __align__(16) unsigned char smem_raw[49152];  // 48 KB arena
    const int t = threadIdx.x;

    // ---------------- phase 1: triple pooling (512 blocks = b*4 + cblk) ----
    {
        float* cpart  = (float*)smem_raw;   // [16][4]
        float* hsum_l = cpart + 64;         // [64]
        float* wpart  = hsum_l + 64;        // [4][64]

        const int blk  = blockIdx.x;
        const int b    = blk >> 2;
        const int cblk = blk & 3;
        const int wvv  = t >> 6;
        const int l    = t & 63;
        const int lg   = l >> 4;
        const int lw   = l & 15;

        const float* xb = x + (size_t)b * 262144 + (size_t)cblk * 65536;

        float cs[16];
        float acc_h[4] = {0.f, 0.f, 0.f, 0.f};
        float acc_w[4] = {0.f, 0.f, 0.f, 0.f};

#pragma unroll
        for (int cc = 0; cc < 16; ++cc) {
            const float* xc = xb + cc * 4096 + wvv * 1024 + 4 * l;
            float sc = 0.f;
#pragma unroll
            for (int k = 0; k < 4; ++k) {
                float4 v = *reinterpret_cast<const float4*>(xc + k * 256);
                float s = (v.x + v.y) + (v.z + v.w);
                sc += s;
                acc_h[k] += s;
                acc_w[0] += v.x; acc_w[1] += v.y; acc_w[2] += v.z; acc_w[3] += v.w;
            }
            cs[cc] = sc;
        }

#pragma unroll
        for (int cc = 0; cc < 16; ++cc) {
            float v = cs[cc];
#pragma unroll
            for (int off = 32; off >= 1; off >>= 1) v += __shfl_xor(v, off, 64);
            if (l == 0) cpart[cc * 4 + wvv] = v;
        }
#pragma unroll
        for (int k = 0; k < 4; ++k) {
            float v = acc_h[k];
            v += __shfl_xor(v, 1, 64);
            v += __shfl_xor(v, 2, 64);
            v += __shfl_xor(v, 4, 64);
            v += __shfl_xor(v, 8, 64);
            if (lw == 0) hsum_l[wvv * 16 + k * 4 + lg] = v;
        }
#pragma unroll
        for (int m = 0; m < 4; ++m) {
            float v = acc_w[m];
            v += __shfl_xor(v, 16, 64);
            v += __shfl_xor(v, 32, 64);
            if (lg == 0) wpart[wvv * 64 + lw * 4 + m] = v;
        }
        __syncthreads();

        const float scale = 1.f / 4096.f;
        if (t < 16) {
            float s = cpart[t * 4 + 0] + cpart[t * 4 + 1] + cpart[t * 4 + 2] + cpart[t * 4 + 3];
            cvecT[(cblk * 16 + t) * NB + b] = s * scale;
        }
        if (t < 64) {
            wv_part[(cblk * 64 + t) * NB + b] = hsum_l[t] * scale;                        // per-h
            float ws_ = wpart[0 * 64 + t] + wpart[1 * 64 + t] + wpart[2 * 64 + t] + wpart[3 * 64 + t];
            hv_part[(cblk * 64 + t) * NB + b] = ws_ * scale;                              // per-w
        }
    }
    grid_barrier(&bar[0], 512);

    // ---------------- phase 2: fvec (blocks 0..191 = br*64 + i) ------------
    if (blockIdx.x < 192) {
        float* Wt = (float*)smem_raw;   // [64][64]  Wt[j][o]
        float* vl = Wt + 4096;          // [64][NB]  vl[j][b]

        const int br = blockIdx.x >> 6;
        const int i  = blockIdx.x & 63;
        const float* W = (br == 0) ? Wc : (br == 1) ? Wh : Ww;
        const float* V = (br == 0) ? cvecT : (br == 1) ? hv_part : wv_part;
        unsigned short* outT = (br == 0) ? fcT : (br == 1) ? fhT : fwT;

        {
            const float* Wi = W + (size_t)i * 4096;
#pragma unroll
            for (int r = 0; r < 4; ++r) {
                int f = t + 256 * r;
                float4 v = reinterpret_cast<const float4*>(Wi)[f];
                int o = (4 * f) >> 6;
                int j = (4 * f) & 63;
                Wt[(j + 0) * 64 + o] = v.x; Wt[(j + 1) * 64 + o] = v.y;
                Wt[(j + 2) * 64 + o] = v.z; Wt[(j + 3) * 64 + o] = v.w;
            }
        }
#pragma unroll
        for (int r = 0; r < 8; ++r) {
            int f = t + 256 * r;
            float4 v = reinterpret_cast<const float4*>(V)[f];
            if (br != 0) {
#pragma unroll
                for (int k = 1; k < 4; ++k) {
                    float4 u = reinterpret_cast<const float4*>(V + 8192 * k)[f];
                    v.x += u.x; v.y += u.y; v.z += u.z; v.w += u.w;
                }
            }
            reinterpret_cast<float4*>(vl)[f] = v;
        }
        __syncthreads();

        const int og = t & 7;
        const int bg = t >> 3;
        const int o0 = og * 8;
        const int b0 = bg * 4;

        float acc[4][8];
#pragma unroll
        for (int bb = 0; bb < 4; ++bb)
#pragma unroll
            for (int oo = 0; oo < 8; ++oo) acc[bb][oo] = 0.f;

#pragma unroll 4
        for (int j = 0; j < 64; ++j) {
            float4 vb = *reinterpret_cast<const float4*>(&vl[j * NB + b0]);
            float4 w0 = *reinterpret_cast<const float4*>(&Wt[j * 64 + o0]);
            float4 w1 = *reinterpret_cast<const float4*>(&Wt[j * 64 + o0 + 4]);
            float vb_[4] = {vb.x, vb.y, vb.z, vb.w};
            float wv_[8] = {w0.x, w0.y, w0.z, w0.w, w1.x, w1.y, w1.z, w1.w};
#pragma unroll
            for (int bb = 0; bb < 4; ++bb)
#pragma unroll
                for (int oo = 0; oo < 8; ++oo)
                    acc[bb][oo] += vb_[bb] * wv_[oo];
        }

#pragma unroll
        for (int bb = 0; bb < 4; ++bb)
#pragma unroll
            for (int oo = 0; oo < 8; ++oo) {
                float sg = 1.f / (1.f + __expf(-acc[bb][oo]));
                outT[((size_t)(b0 + bb) * 64 + (o0 + oo)) * 64 + i] = f2bf(sg);
            }
    }
    grid_barrier(&bar[1], 512);

    // ---------------- phase 3: c-sweep MFMA recon (512 blocks = b*4+cq) ----
    {
        unsigned short* fhl = (unsigned short*)smem_raw;  // [64][72]  [p][k]
        unsigned short* fwl = fhl + 64 * 72;              // [64][72]  [q][k]
        unsigned short* fcl = fwl + 64 * 72;              // [16][72]  [c][k]

        const int blk = blockIdx.x;
        const int b   = blk >> 2;
        const int cq  = blk & 3;
        const int w   = t >> 6;
        const int l   = t & 63;
        const int lr  = l & 15;
        const int lg4 = l >> 4;

        const unsigned short* fhb = fhT + (size_t)b * 4096;
        const unsigned short* fwb = fwT + (size_t)b * 4096;
        const unsigned short* fcb = fcT + (size_t)b * 4096 + cq * 1024;

#pragma unroll
        for (int r = 0; r < 2; ++r) {
            int f = t + 256 * r;
            *reinterpret_cast<int4*>(&fhl[(f >> 3) * 72 + (f & 7) * 8]) =
                reinterpret_cast<const int4*>(fhb)[f];
            *reinterpret_cast<int4*>(&fwl[(f >> 3) * 72 + (f & 7) * 8]) =
                reinterpret_cast<const int4*>(fwb)[f];
        }
        if (t < 128) {
            *reinterpret_cast<int4*>(&fcl[(t >> 3) * 72 + (t & 7) * 8]) =
                reinterpret_cast<const int4*>(fcb)[t];
        }
        __syncthreads();

        bf16x8 afw[4][2];
#pragma unroll
        for (int qt = 0; qt < 4; ++qt)
#pragma unroll
            for (int kb = 0; kb < 2; ++kb)
                afw[qt][kb] = *reinterpret_cast<const bf16x8*>(
                    &fwl[(qt * 16 + lr) * 72 + kb * 32 + lg4 * 8]);

        float hvf[4][2][8];
#pragma unroll
        for (int pt = 0; pt < 4; ++pt)
#pragma unroll
            for (int kb = 0; kb < 2; ++kb) {
                bf16x8 h = *reinterpret_cast<const bf16x8*>(
                    &fhl[(pt * 16 + lr) * 72 + kb * 32 + lg4 * 8]);
#pragma unroll
                for (int j = 0; j < 8; ++j) hvf[pt][kb][j] = bf2f(h[j]);
            }

        for (int cc = 0; cc < 4; ++cc) {
            const int cl = w * 4 + cc;     // local c 0..15
            float cvf[16];
#pragma unroll
            for (int kb = 0; kb < 2; ++kb) {
                bf16x8 cf = *reinterpret_cast<const bf16x8*>(
                    &fcl[cl * 72 + kb * 32 + lg4 * 8]);
#pragma unroll
                for (int j = 0; j < 8; ++j) cvf[kb * 8 + j] = bf2f(cf[j]);
            }
            bf16x8 bp[4][2];
#pragma unroll
            for (int pt = 0; pt < 4; ++pt)
#pragma unroll
                for (int kb = 0; kb < 2; ++kb) {
                    union { unsigned u[4]; bf16x8 v; } bu;
#pragma unroll
                    for (int jj = 0; jj < 4; ++jj) {
                        float p0 = cvf[kb * 8 + 2 * jj]     * hvf[pt][kb][2 * jj];
                        float p1 = cvf[kb * 8 + 2 * jj + 1] * hvf[pt][kb][2 * jj + 1];
                        bu.u[jj] = packbf2(p0, p1);
                    }
                    bp[pt][kb] = bu.v;
                }
            float* oc = out + (((size_t)b * 64 + cq * 16 + cl) * 64) * 64;
#pragma unroll
            for (int pt = 0; pt < 4; ++pt)
#pragma unroll
                for (int qt = 0; qt < 4; ++qt) {
                    f32x4 a = {0.f, 0.f, 0.f, 0.f};
                    a = __builtin_amdgcn_mfma_f32_16x16x32_bf16(afw[qt][0], bp[pt][0], a, 0, 0, 0);
                    a = __builtin_amdgcn_mfma_f32_16x16x32_bf16(afw[qt][1], bp[pt][1], a, 0, 0, 0);
                    float4 v; v.x = a[0]; v.y = a[1]; v.z = a[2]; v.w = a[3];
                    *reinterpret_cast<float4*>(
                        oc + ((size_t)(pt * 16 + lr) * 64) + qt * 16 + lg4 * 4) = v;
                }
        }
    }
}

// ---------------------------------------------------------------------------
extern "C" void kernel_launch(void* const* d_in, const int* in_sizes, int n_in,
                              void* d_out, int out_size, void* d_ws, size_t ws_size,
                              hipStream_t stream) {
    (void)in_sizes; (void)n_in; (void)out_size; (void)ws_size;
    const float* x  = (const float*)d_in[0];
    const float* Wc = (const float*)d_in[1];
    const float* Wh = (const float*)d_in[2];
    const float* Ww = (const float*)d_in[3];
    float* out = (float*)d_out;

    float* ws      = (float*)d_ws;
    float* cvecT   = ws;                 // 64*128 f32
    float* hv_part = ws + 8192;          // 4*64*128 f32
    float* wv_part = ws + 40960;         // 4*64*128 f32
    unsigned short* fcT = (unsigned short*)(ws + 73728);  // 128*64*64 bf16 each
    unsigned short* fhT = fcT + 524288;
    unsigned short* fwT = fhT + 524288;
    unsigned* bar = (unsigned*)(ws + 73728 + 786432);     // 2 counters

    hipMemsetAsync(bar, 0, 2 * sizeof(unsigned), stream);
    fused_kernel<<<512, 256, 0, stream>>>(x, Wc, Wh, Ww, cvecT, hv_part, wv_part,
                                          fcT, fhT, fwT, bar, out);
}

// Round 11
// 166.730 us; speedup vs baseline: 1.4336x; 1.4336x over previous
//
#include <hip/hip_runtime.h>
#include <hip/hip_bf16.h>

// B=128, D=64.
//   c_vec[b,c] = mean_{h,w} x[b,c,h,w]
//   h_vec[b,w] = mean_{c,h} x[b,c,h,w]
//   w_vec[b,h] = mean_{c,w} x[b,c,h,w]
//   f*[b,i,o] = sigmoid(sum_j W*[i,o,j] * vec[b,j])
//   LR[b,c,p,q] = sum_i fc[b,i,c]*fh[b,i,p]*fw[b,i,q]
// R11: fused kernel v2. R10 proved barrier+fence correct but 8 waves/CU
// starved the pool phase (1.35 TB/s). Now 256 blocks x 1024 threads =
// 16 waves/CU (1 block/CU), matching standalone pool's proven occupancy.

#define NB 128

typedef __attribute__((ext_vector_type(8))) short bf16x8;
typedef __attribute__((ext_vector_type(4))) float f32x4;

__device__ __forceinline__ float bf2f(short s) {
    return __uint_as_float(((unsigned)(unsigned short)s) << 16);
}
__device__ __forceinline__ unsigned packbf2(float a, float b) {
    unsigned ua = __float_as_uint(a); ua += 0x7fffu + ((ua >> 16) & 1u);
    unsigned ub = __float_as_uint(b); ub += 0x7fffu + ((ub >> 16) & 1u);
    return (ua >> 16) | (ub & 0xffff0000u);
}
__device__ __forceinline__ unsigned short f2bf(float f) {
    unsigned u = __float_as_uint(f); u += 0x7fffu + ((u >> 16) & 1u);
    return (unsigned short)(u >> 16);
}

// Grid barrier (verified correct in R10): device-scope release/acquire.
__device__ __forceinline__ void grid_barrier(unsigned* cnt, unsigned target) {
    __syncthreads();
    if (threadIdx.x == 0) {
        __threadfence();
        atomicAdd(cnt, 1u);
        while (__hip_atomic_load(cnt, __ATOMIC_RELAXED,
                                 __HIP_MEMORY_SCOPE_AGENT) < target) {
            __builtin_amdgcn_s_sleep(2);
        }
        __threadfence();
    }
    __syncthreads();
}

__global__ __launch_bounds__(1024, 4) void fused_kernel(
    const float* __restrict__ x,
    const float* __restrict__ Wc,
    const float* __restrict__ Wh,
    const float* __restrict__ Ww,
    float* __restrict__ cvecT,    // [64][128]
    float* __restrict__ hv_part,  // [2][64][128] per-w (ref h_vec)
    float* __restrict__ wv_part,  // [2][64][128] per-h (ref w_vec)
    unsigned short* __restrict__ fcT,  // bf16 [b][o][i]
    unsigned short* __restrict__ fhT,
    unsigned short* __restrict__ fwT,
    unsigned* __restrict__ bar,        // 2 counters, zeroed per call
    float* __restrict__ out)
{
    __shared__ __align__(16) unsigned char smem_raw[49152];  // 48 KB arena
    const int t  = threadIdx.x;
    const int wv = t >> 6;    // wave 0..15
    const int l  = t & 63;
    const int lg = l >> 4;    // 0..3
    const int lw = l & 15;

    // ---------------- phase 1: triple pooling (256 blocks = b*2 + half) ----
    {
        float* hsum_l = (float*)smem_raw;   // [16][64] per-wave h-sums
        float* wsum_l = hsum_l + 1024;      // [16][64] per-wave w-sums

        const int b    = blockIdx.x >> 1;
        const int half = blockIdx.x & 1;

        // wave wv owns c-planes c = half*32 + wv*2 + {0,1}, full 4096 elems each
        const float* xb = x + (size_t)b * 262144 + (size_t)half * 131072
                            + (size_t)wv * 8192;

        float acc_h[16];
        float acc_w[4] = {0.f, 0.f, 0.f, 0.f};
        float csum[2];
#pragma unroll
        for (int k = 0; k < 16; ++k) acc_h[k] = 0.f;

#pragma unroll
        for (int cc = 0; cc < 2; ++cc) {
            const float* xc = xb + cc * 4096 + 4 * l;
            float sc = 0.f;
#pragma unroll
            for (int k = 0; k < 16; ++k) {
                float4 v = *reinterpret_cast<const float4*>(xc + k * 256);
                float s = (v.x + v.y) + (v.z + v.w);
                sc += s;
                acc_h[k] += s;   // h = lg + 4k
                acc_w[0] += v.x; acc_w[1] += v.y; acc_w[2] += v.z; acc_w[3] += v.w;
            }
            csum[cc] = sc;
        }

        const float scale = 1.f / 4096.f;
        // c-sums: full-wave reduce, exclusive write
#pragma unroll
        for (int cc = 0; cc < 2; ++cc) {
            float v = csum[cc];
#pragma unroll
            for (int off = 32; off >= 1; off >>= 1) v += __shfl_xor(v, off, 64);
            if (l == 0) cvecT[(half * 32 + wv * 2 + cc) * NB + b] = v * scale;
        }
        // h-sums (-> w_vec): reduce over lw lanes
#pragma unroll
        for (int k = 0; k < 16; ++k) {
            float v = acc_h[k];
            v += __shfl_xor(v, 1, 64);
            v += __shfl_xor(v, 2, 64);
            v += __shfl_xor(v, 4, 64);
            v += __shfl_xor(v, 8, 64);
            if (lw == 0) hsum_l[wv * 64 + lg + 4 * k] = v;
        }
        // w-sums (-> h_vec): reduce over lg lanes
#pragma unroll
        for (int m = 0; m < 4; ++m) {
            float v = acc_w[m];
            v += __shfl_xor(v, 16, 64);
            v += __shfl_xor(v, 32, 64);
            if (lg == 0) wsum_l[wv * 64 + lw * 4 + m] = v;
        }
        __syncthreads();

        if (t < 64) {
            float sh = 0.f, sw = 0.f;
#pragma unroll
            for (int w2 = 0; w2 < 16; ++w2) {
                sh += hsum_l[w2 * 64 + t];
                sw += wsum_l[w2 * 64 + t];
            }
            wv_part[(half * 64 + t) * NB + b] = sh * scale;   // per-h
            hv_part[(half * 64 + t) * NB + b] = sw * scale;   // per-w
        }
    }
    grid_barrier(&bar[0], 256);

    // ---------------- phase 2: fvec (blocks 0..191 = br*64 + i) ------------
    if (blockIdx.x < 192) {
        float* Wt = (float*)smem_raw;   // [64][64]  Wt[j][o] 16KB
        float* vl = Wt + 4096;          // [64][NB]  vl[j][b] 32KB

        const int br = blockIdx.x >> 6;
        const int i  = blockIdx.x & 63;
        const float* W = (br == 0) ? Wc : (br == 1) ? Wh : Ww;
        const float* V = (br == 0) ? cvecT : (br == 1) ? hv_part : wv_part;
        unsigned short* outT = (br == 0) ? fcT : (br == 1) ? fhT : fwT;

        {   // stage Wt transposed: 1024 float4, one per thread
            float4 v = reinterpret_cast<const float4*>(W + (size_t)i * 4096)[t];
            int o = (4 * t) >> 6;
            int j = (4 * t) & 63;
            Wt[(j + 0) * 64 + o] = v.x; Wt[(j + 1) * 64 + o] = v.y;
            Wt[(j + 2) * 64 + o] = v.z; Wt[(j + 3) * 64 + o] = v.w;
        }
#pragma unroll
        for (int r = 0; r < 2; ++r) {   // stage vl: 2048 float4 (+depth-2 sum)
            int f = t + 1024 * r;
            float4 v = reinterpret_cast<const float4*>(V)[f];
            if (br != 0) {
                float4 u = reinterpret_cast<const float4*>(V)[f + 2048];
                v.x += u.x; v.y += u.y; v.z += u.z; v.w += u.w;
            }
            reinterpret_cast<float4*>(vl)[f] = v;
        }
        __syncthreads();

        const int og = t & 15;   // 16 groups of 4 o
        const int bg = t >> 4;   // 64 groups of 2 b
        const int o0 = og * 4;
        const int b0 = bg * 2;

        float acc[2][4];
#pragma unroll
        for (int bb = 0; bb < 2; ++bb)
#pragma unroll
            for (int oo = 0; oo < 4; ++oo) acc[bb][oo] = 0.f;

#pragma unroll 4
        for (int j = 0; j < 64; ++j) {
            float2 vb = *reinterpret_cast<const float2*>(&vl[j * NB + b0]);
            float4 w0 = *reinterpret_cast<const float4*>(&Wt[j * 64 + o0]);
            float vb_[2] = {vb.x, vb.y};
            float wv_[4] = {w0.x, w0.y, w0.z, w0.w};
#pragma unroll
            for (int bb = 0; bb < 2; ++bb)
#pragma unroll
                for (int oo = 0; oo < 4; ++oo)
                    acc[bb][oo] += vb_[bb] * wv_[oo];
        }

#pragma unroll
        for (int bb = 0; bb < 2; ++bb)
#pragma unroll
            for (int oo = 0; oo < 4; ++oo) {
                float sg = 1.f / (1.f + __expf(-acc[bb][oo]));
                outT[((size_t)(b0 + bb) * 64 + (o0 + oo)) * 64 + i] = f2bf(sg);
            }
    }
    grid_barrier(&bar[1], 256);

    // ---------------- phase 3: c-sweep MFMA recon (256 blocks = b*2+qh) ----
    {
        unsigned short* fhl = (unsigned short*)smem_raw;  // [64][72] [p][k]
        unsigned short* fwl = fhl + 64 * 72;              // [64][72] [q][k]
        unsigned short* fcl = fwl + 64 * 72;              // [16][72] [c][k]

        const int b  = blockIdx.x >> 1;
        const int qh = blockIdx.x & 1;   // cq in {2qh, 2qh+1}
        const int lr  = l & 15;
        const int lg4 = l >> 4;

        const unsigned short* fhb = fhT + (size_t)b * 4096;
        const unsigned short* fwb = fwT + (size_t)b * 4096;

        // stage fhl/fwl once: 512 int4 each
        if (t < 512) {
            *reinterpret_cast<int4*>(&fhl[(t >> 3) * 72 + (t & 7) * 8]) =
                reinterpret_cast<const int4*>(fhb)[t];
        } else {
            int f = t - 512;
            *reinterpret_cast<int4*>(&fwl[(f >> 3) * 72 + (f & 7) * 8]) =
                reinterpret_cast<const int4*>(fwb)[f];
        }
        __syncthreads();

        bf16x8 afw[4][2], hfr[4][2];
#pragma unroll
        for (int qt = 0; qt < 4; ++qt)
#pragma unroll
            for (int kb = 0; kb < 2; ++kb) {
                afw[qt][kb] = *reinterpret_cast<const bf16x8*>(
                    &fwl[(qt * 16 + lr) * 72 + kb * 32 + lg4 * 8]);
                hfr[qt][kb] = *reinterpret_cast<const bf16x8*>(
                    &fhl[(qt * 16 + lr) * 72 + kb * 32 + lg4 * 8]);
            }

        for (int cqi = 0; cqi < 2; ++cqi) {
            const int cq = qh * 2 + cqi;
            __syncthreads();   // protect fcl reuse across iterations
            if (t < 128) {
                *reinterpret_cast<int4*>(&fcl[(t >> 3) * 72 + (t & 7) * 8]) =
                    reinterpret_cast<const int4*>(fcT + (size_t)b * 4096 + cq * 1024)[t];
            }
            __syncthreads();

            const int cl = wv;   // wave owns c_local 0..15
            float cvf[16];
#pragma unroll
            for (int kb = 0; kb < 2; ++kb) {
                bf16x8 cf = *reinterpret_cast<const bf16x8*>(
                    &fcl[cl * 72 + kb * 32 + lg4 * 8]);
#pragma unroll
                for (int j = 0; j < 8; ++j) cvf[kb * 8 + j] = bf2f(cf[j]);
            }
            bf16x8 bp[4][2];
#pragma unroll
            for (int pt = 0; pt < 4; ++pt)
#pragma unroll
                for (int kb = 0; kb < 2; ++kb) {
                    union { unsigned u[4]; bf16x8 v; } bu;
#pragma unroll
                    for (int jj = 0; jj < 4; ++jj) {
                        float p0 = cvf[kb * 8 + 2 * jj]     * bf2f(hfr[pt][kb][2 * jj]);
                        float p1 = cvf[kb * 8 + 2 * jj + 1] * bf2f(hfr[pt][kb][2 * jj + 1]);
                        bu.u[jj] = packbf2(p0, p1);
                    }
                    bp[pt][kb] = bu.v;
                }
            float* oc = out + (((size_t)b * 64 + cq * 16 + cl) * 64) * 64;
#pragma unroll
            for (int pt = 0; pt < 4; ++pt)
#pragma unroll
                for (int qt = 0; qt < 4; ++qt) {
                    f32x4 a = {0.f, 0.f, 0.f, 0.f};
                    a = __builtin_amdgcn_mfma_f32_16x16x32_bf16(afw[qt][0], bp[pt][0], a, 0, 0, 0);
                    a = __builtin_amdgcn_mfma_f32_16x16x32_bf16(afw[qt][1], bp[pt][1], a, 0, 0, 0);
                    float4 v; v.x = a[0]; v.y = a[1]; v.z = a[2]; v.w = a[3];
                    *reinterpret_cast<float4*>(
                        oc + ((size_t)(pt * 16 + lr) * 64) + qt * 16 + lg4 * 4) = v;
                }
        }
    }
}

// ---------------------------------------------------------------------------
extern "C" void kernel_launch(void* const* d_in, const int* in_sizes, int n_in,
                              void* d_out, int out_size, void* d_ws, size_t ws_size,
                              hipStream_t stream) {
    (void)in_sizes; (void)n_in; (void)out_size; (void)ws_size;
    const float* x  = (const float*)d_in[0];
    const float* Wc = (const float*)d_in[1];
    const float* Wh = (const float*)d_in[2];
    const float* Ww = (const float*)d_in[3];
    float* out = (float*)d_out;

    float* ws      = (float*)d_ws;
    float* cvecT   = ws;                 // 64*128 f32
    float* hv_part = ws + 8192;          // 2*64*128 f32
    float* wv_part = ws + 24576;         // 2*64*128 f32
    unsigned short* fcT = (unsigned short*)(ws + 40960);  // 128*64*64 bf16 each
    unsigned short* fhT = fcT + 524288;
    unsigned short* fwT = fhT + 524288;
    unsigned* bar = (unsigned*)(fwT + 524288);            // 2 counters

    hipMemsetAsync(bar, 0, 2 * sizeof(unsigned), stream);
    fused_kernel<<<256, 1024, 0, stream>>>(x, Wc, Wh, Ww, cvecT, hv_part, wv_part,
                                           fcT, fhT, fwT, bar, out);
}